// Round 1
// baseline (239.974 us; speedup 1.0000x reference)
//
#include <hip/hip_runtime.h>

#define NBINS 256
#define NCH 3
// H*W = 512*512 = 262144 = 2^18; per-float4 index: HW/4 = 65536 = 2^16
#define HW_LOG2 18
#define NHIST (2 * NCH * NBINS)   // 1536 bins total (input + label)

// ---------------------------------------------------------------------------
// Histogram kernel: grid-stride over float4s of both arrays simultaneously.
// Per-block LDS histograms (6 KB), merged to global d_ws with atomics.
// ---------------------------------------------------------------------------
__global__ __launch_bounds__(256) void hist_kernel(
    const float* __restrict__ a, const float* __restrict__ b,
    unsigned int* __restrict__ gh, long long n4) {
    __shared__ unsigned int sh[NHIST];
    const int tid = threadIdx.x;
    for (int i = tid; i < NHIST; i += blockDim.x) sh[i] = 0u;
    __syncthreads();

    const float4* __restrict__ a4 = (const float4*)a;
    const float4* __restrict__ b4 = (const float4*)b;
    const long long stride = (long long)gridDim.x * blockDim.x;

    for (long long i = (long long)blockIdx.x * blockDim.x + tid; i < n4; i += stride) {
        // channel of the 4 consecutive elems (all same ch: HW divisible by 4)
        const int ch = (int)((i >> (HW_LOG2 - 2)) % 3);
        unsigned int* __restrict__ ha = &sh[ch * NBINS];
        unsigned int* __restrict__ hb = &sh[(NCH + ch) * NBINS];

        const float4 va = a4[i];
        const float4 vb = b4[i];

        // bin = (int)clip(v, 0, 255): truncation == floor for nonneg values
        atomicAdd(&ha[(int)fminf(fmaxf(va.x, 0.f), 255.f)], 1u);
        atomicAdd(&ha[(int)fminf(fmaxf(va.y, 0.f), 255.f)], 1u);
        atomicAdd(&ha[(int)fminf(fmaxf(va.z, 0.f), 255.f)], 1u);
        atomicAdd(&ha[(int)fminf(fmaxf(va.w, 0.f), 255.f)], 1u);
        atomicAdd(&hb[(int)fminf(fmaxf(vb.x, 0.f), 255.f)], 1u);
        atomicAdd(&hb[(int)fminf(fmaxf(vb.y, 0.f), 255.f)], 1u);
        atomicAdd(&hb[(int)fminf(fmaxf(vb.z, 0.f), 255.f)], 1u);
        atomicAdd(&hb[(int)fminf(fmaxf(vb.w, 0.f), 255.f)], 1u);
    }
    __syncthreads();

    for (int i = tid; i < NHIST; i += blockDim.x) {
        const unsigned int v = sh[i];
        if (v) atomicAdd(&gh[i], v);
    }
}

// ---------------------------------------------------------------------------
// Final Bhattacharyya kernel: 1 block × 256 threads, fp64 reduction.
// d = sum_ch sqrt(max(1 - s_ch / (sqrt(mean1*mean2)*256), 0))
// ---------------------------------------------------------------------------
__device__ __forceinline__ double block_reduce256(double v, double* sh4) {
    const int t = threadIdx.x;
    const int lane = t & 63, w = t >> 6;
    #pragma unroll
    for (int o = 32; o > 0; o >>= 1) v += __shfl_down(v, o, 64);
    if (lane == 0) sh4[w] = v;
    __syncthreads();
    double r = sh4[0] + sh4[1] + sh4[2] + sh4[3];
    __syncthreads();
    return r;
}

__global__ __launch_bounds__(256) void bhat_kernel(
    const unsigned int* __restrict__ gh, float* __restrict__ out) {
    __shared__ double sh4[4];
    const int t = threadIdx.x;  // bin index
    double result = 0.0;
    #pragma unroll
    for (int ch = 0; ch < NCH; ++ch) {
        const double h1 = (double)gh[ch * NBINS + t];
        const double h2 = (double)gh[(NCH + ch) * NBINS + t];
        const double s  = block_reduce256(sqrt(h1 * h2), sh4);
        const double s1 = block_reduce256(h1, sh4);
        const double s2 = block_reduce256(h2, sh4);
        const double denom = sqrt((s1 / (double)NBINS) * (s2 / (double)NBINS)) * (double)NBINS;
        const double v = 1.0 - s / denom;
        result += sqrt(v > 0.0 ? v : 0.0);
    }
    if (t == 0) out[0] = (float)result;
}

extern "C" void kernel_launch(void* const* d_in, const int* in_sizes, int n_in,
                              void* d_out, int out_size, void* d_ws, size_t ws_size,
                              hipStream_t stream) {
    const float* input = (const float*)d_in[0];
    const float* label = (const float*)d_in[1];
    float* out = (float*)d_out;
    unsigned int* gh = (unsigned int*)d_ws;

    const long long n  = (long long)in_sizes[0];  // 25,165,824
    const long long n4 = n / 4;

    // d_ws is poisoned with 0xAA before every timed launch — zero the hists.
    hipMemsetAsync(gh, 0, NHIST * sizeof(unsigned int), stream);

    const int block = 256;
    const int grid = 2048;  // 8 blocks/CU on 256 CUs
    hist_kernel<<<grid, block, 0, stream>>>(input, label, gh, n4);
    bhat_kernel<<<1, 256, 0, stream>>>(gh, out);
}

// Round 2
// 237.235 us; speedup vs baseline: 1.0115x; 1.0115x over previous
//
#include <hip/hip_runtime.h>

#define NBINS 256
#define NCH 3
#define NHIST (2 * NCH * NBINS)   // 1536 global bins (input + label)
#define HW 262144                  // 512*512
#define HW4 65536                  // HW/4 float4s per (batch,channel) plane
#define BATCH 32
#define JOB_N4 (BATCH * HW4)       // 2,097,152 float4s per (array,channel) job
#define BLOCKS_PER_JOB 384
#define THREADS 256

// ---------------------------------------------------------------------------
// Histogram kernel, atomic-free main loop.
// Grid = 6 jobs x 384 blocks; job = (array, channel) so each lane's private
// histogram only needs 256 bins. Per-lane u8x4-packed counters in LDS:
//   word index = wave*4096 + (bin>>2)*64 + lane   (bank = lane%32, 2-way free)
// Worst case per-lane count = ceil(JOB_N4/(384*256))*4 = 88 < 255 -> u8 safe
// for ANY input. Flush: per-bin byte extraction + one global atomic per bin.
// ---------------------------------------------------------------------------
__device__ __forceinline__ void bump(unsigned int* lbase, float v) {
    const int bin = (int)fminf(fmaxf(v, 0.f), 255.f);  // trunc==floor, v>=0
    unsigned int* p = lbase + (bin >> 2) * 64;
    *p += 1u << ((bin & 3) << 3);
}

__global__ __launch_bounds__(THREADS) void hist_kernel(
    const float* __restrict__ a, const float* __restrict__ b,
    unsigned int* __restrict__ gh) {
    __shared__ unsigned int sh[16384];  // 64 KB = 4 waves * 64 lanes * 64 words
    const int tid  = threadIdx.x;
    const int wave = tid >> 6;
    const int lane = tid & 63;

    // zero LDS (16384 words / 256 threads = 64 words = 16 uint4 each)
    uint4* shv = (uint4*)sh;
    #pragma unroll
    for (int i = 0; i < 16; ++i)
        shv[tid + i * THREADS] = make_uint4(0u, 0u, 0u, 0u);
    __syncthreads();

    const int job        = blockIdx.x / BLOCKS_PER_JOB;  // 0..5
    const int blockInJob = blockIdx.x % BLOCKS_PER_JOB;
    const int arr = job / NCH;   // 0 = input, 1 = label
    const int ch  = job % NCH;

    const float4* __restrict__ src = (const float4*)(arr ? b : a);
    unsigned int* const lbase = &sh[wave * 4096 + lane];

    const unsigned stride = BLOCKS_PER_JOB * THREADS;
    for (unsigned i = blockInJob * THREADS + tid; i < JOB_N4; i += 2 * stride) {
        const unsigned j = i + stride;
        // jobElem4 -> global float4 index: batch = i>>16, pos = i & 65535
        const unsigned gi = ((i >> 16) * NCH + ch) * HW4 + (i & (HW4 - 1));
        const float4 va = src[gi];
        const bool pb = (j < JOB_N4);
        float4 vb;
        if (pb) {
            const unsigned gj = ((j >> 16) * NCH + ch) * HW4 + (j & (HW4 - 1));
            vb = src[gj];  // issued before the DS ops below -> 2 loads in flight
        }
        bump(lbase, va.x); bump(lbase, va.y);
        bump(lbase, va.z); bump(lbase, va.w);
        if (pb) {
            bump(lbase, vb.x); bump(lbase, vb.y);
            bump(lbase, vb.z); bump(lbase, vb.w);
        }
    }
    __syncthreads();

    // Flush: thread t owns bin t. Sum its byte over 4 waves x 64 lanes,
    // reading uint4 (4 lanes at once), chunk-swizzled to spread banks.
    unsigned int sum = 0;
    const int grp = tid >> 2;          // bin>>2 : word group within lane region
    const int sh8 = (tid & 3) << 3;    // byte shift within word
    #pragma unroll
    for (int w = 0; w < 4; ++w) {
        const unsigned int* base = &sh[w * 4096 + grp * 64];
        #pragma unroll
        for (int c = 0; c < 16; ++c) {
            const int cc = (c + tid) & 15;
            const uint4 q = *(const uint4*)(base + cc * 4);
            sum += ((q.x >> sh8) & 0xFFu) + ((q.y >> sh8) & 0xFFu)
                 + ((q.z >> sh8) & 0xFFu) + ((q.w >> sh8) & 0xFFu);
        }
    }
    atomicAdd(&gh[(arr * NCH + ch) * NBINS + tid], sum);
}

// ---------------------------------------------------------------------------
// Final Bhattacharyya kernel: 1 block x 256 threads, fp64 reduction.
// ---------------------------------------------------------------------------
__device__ __forceinline__ double block_reduce256(double v, double* sh4) {
    const int t = threadIdx.x;
    const int lane = t & 63, w = t >> 6;
    #pragma unroll
    for (int o = 32; o > 0; o >>= 1) v += __shfl_down(v, o, 64);
    if (lane == 0) sh4[w] = v;
    __syncthreads();
    double r = sh4[0] + sh4[1] + sh4[2] + sh4[3];
    __syncthreads();
    return r;
}

__global__ __launch_bounds__(256) void bhat_kernel(
    const unsigned int* __restrict__ gh, float* __restrict__ out) {
    __shared__ double sh4[4];
    const int t = threadIdx.x;  // bin index
    double result = 0.0;
    #pragma unroll
    for (int ch = 0; ch < NCH; ++ch) {
        const double h1 = (double)gh[ch * NBINS + t];
        const double h2 = (double)gh[(NCH + ch) * NBINS + t];
        const double s  = block_reduce256(sqrt(h1 * h2), sh4);
        const double s1 = block_reduce256(h1, sh4);
        const double s2 = block_reduce256(h2, sh4);
        const double denom = sqrt((s1 / (double)NBINS) * (s2 / (double)NBINS)) * (double)NBINS;
        const double v = 1.0 - s / denom;
        result += sqrt(v > 0.0 ? v : 0.0);
    }
    if (t == 0) out[0] = (float)result;
}

extern "C" void kernel_launch(void* const* d_in, const int* in_sizes, int n_in,
                              void* d_out, int out_size, void* d_ws, size_t ws_size,
                              hipStream_t stream) {
    const float* input = (const float*)d_in[0];
    const float* label = (const float*)d_in[1];
    float* out = (float*)d_out;
    unsigned int* gh = (unsigned int*)d_ws;

    // d_ws is poisoned with 0xAA before every timed launch — zero the hists.
    hipMemsetAsync(gh, 0, NHIST * sizeof(unsigned int), stream);

    hist_kernel<<<6 * BLOCKS_PER_JOB, THREADS, 0, stream>>>(input, label, gh);
    bhat_kernel<<<1, 256, 0, stream>>>(gh, out);
}

// Round 3
// 218.529 us; speedup vs baseline: 1.0981x; 1.0856x over previous
//
#include <hip/hip_runtime.h>

#define NBINS 256
#define NCH 3
#define NHIST (2 * NCH * NBINS)   // 1536 global bins (input + label)
#define HW4 65536                  // 512*512/4 float4s per (batch,channel) plane
#define BATCH 32
#define BLOCKS_PER_JOB 256         // 256 blk * 256 thr = 65536 threads = HW4 exactly
#define THREADS 256

// ---------------------------------------------------------------------------
// Histogram kernel, atomic-free, latency-batched.
// Grid = 6 jobs x 256 blocks; job = (array, channel). Per-lane u8x4-packed
// counters in LDS: word = wave*4096 + (bin>>2)*64 + lane (bank = lane%32,
// free 2-way alias). Each thread owns pos = blockInJob*256+tid and walks all
// 32 batches of its channel -> 32 float4s/thread, max per-bin count 128 < 255.
//
// The RMW chain is batched per float4: 4 ds_reads -> ONE wait -> register
// duplicate-merge -> 4 ds_writes. Duplicates (same lane-word) are forward-
// merged into the highest slot; zeroed slots write back stale values that the
// later full write overwrites (same-wave DS ops to one address are in-order).
// ---------------------------------------------------------------------------
__device__ __forceinline__ void batch4(unsigned int* lbase, float4 v) {
    const int b0 = (int)fminf(fmaxf(v.x, 0.f), 255.f);  // trunc==floor, v>=0
    const int b1 = (int)fminf(fmaxf(v.y, 0.f), 255.f);
    const int b2 = (int)fminf(fmaxf(v.z, 0.f), 255.f);
    const int b3 = (int)fminf(fmaxf(v.w, 0.f), 255.f);
    const int w0 = b0 >> 2, w1 = b1 >> 2, w2 = b2 >> 2, w3 = b3 >> 2;
    unsigned int i0 = 1u << ((b0 & 3) << 3);
    unsigned int i1 = 1u << ((b1 & 3) << 3);
    unsigned int i2 = 1u << ((b2 & 3) << 3);
    unsigned int i3 = 1u << ((b3 & 3) << 3);
    unsigned int* const p0 = lbase + w0 * 64;
    unsigned int* const p1 = lbase + w1 * 64;
    unsigned int* const p2 = lbase + w2 * 64;
    unsigned int* const p3 = lbase + w3 * 64;
    const unsigned int r0 = *p0;
    const unsigned int r1 = *p1;
    const unsigned int r2 = *p2;
    const unsigned int r3 = *p3;
    if (w0 == w1) { i1 += i0; i0 = 0; }
    if (w0 == w2) { i2 += i0; i0 = 0; }
    if (w0 == w3) { i3 += i0; i0 = 0; }
    if (w1 == w2) { i2 += i1; i1 = 0; }
    if (w1 == w3) { i3 += i1; i1 = 0; }
    if (w2 == w3) { i3 += i2; i2 = 0; }
    *p0 = r0 + i0;
    *p1 = r1 + i1;
    *p2 = r2 + i2;
    *p3 = r3 + i3;
}

__global__ __launch_bounds__(THREADS) void hist_kernel(
    const float* __restrict__ a, const float* __restrict__ b,
    unsigned int* __restrict__ gh) {
    __shared__ unsigned int sh[16384];  // 64 KB = 4 waves * 64 lanes * 64 words
    const int tid  = threadIdx.x;
    const int wave = tid >> 6;
    const int lane = tid & 63;

    uint4* shv = (uint4*)sh;
    #pragma unroll
    for (int i = 0; i < 16; ++i)
        shv[tid + i * THREADS] = make_uint4(0u, 0u, 0u, 0u);
    __syncthreads();

    const int job        = blockIdx.x >> 8;        // 0..5
    const int blockInJob = blockIdx.x & 255;
    const int arr = job / NCH;   // 0 = input, 1 = label
    const int ch  = job % NCH;

    const float4* __restrict__ src = (const float4*)(arr ? b : a);
    unsigned int* const lbase = &sh[wave * 4096 + lane];
    const unsigned pos = ((unsigned)blockInJob << 8) | (unsigned)tid;  // 0..65535

    // 8 iterations x 4 batches: all 4 loads issued before any DS work.
    for (int it = 0; it < BATCH / 4; ++it) {
        const int bt = it << 2;
        const float4 v0 = src[(unsigned)(((bt + 0) * NCH + ch) << 16) | pos];
        const float4 v1 = src[(unsigned)(((bt + 1) * NCH + ch) << 16) | pos];
        const float4 v2 = src[(unsigned)(((bt + 2) * NCH + ch) << 16) | pos];
        const float4 v3 = src[(unsigned)(((bt + 3) * NCH + ch) << 16) | pos];
        batch4(lbase, v0);
        batch4(lbase, v1);
        batch4(lbase, v2);
        batch4(lbase, v3);
    }
    __syncthreads();

    // Flush: thread t owns bin t. Sum its byte over 4 waves x 64 lanes,
    // reading uint4 (4 lanes at once), chunk-swizzled to spread banks.
    unsigned int sum = 0;
    const int grp = tid >> 2;          // bin>>2 : word group within lane region
    const int sh8 = (tid & 3) << 3;    // byte shift within word
    #pragma unroll
    for (int w = 0; w < 4; ++w) {
        const unsigned int* base = &sh[w * 4096 + grp * 64];
        #pragma unroll
        for (int c = 0; c < 16; ++c) {
            const int cc = (c + tid) & 15;
            const uint4 q = *(const uint4*)(base + cc * 4);
            sum += ((q.x >> sh8) & 0xFFu) + ((q.y >> sh8) & 0xFFu)
                 + ((q.z >> sh8) & 0xFFu) + ((q.w >> sh8) & 0xFFu);
        }
    }
    atomicAdd(&gh[(arr * NCH + ch) * NBINS + tid], sum);
}

// ---------------------------------------------------------------------------
// Final Bhattacharyya kernel: 1 block x 256 threads, fp64 reduction.
// ---------------------------------------------------------------------------
__device__ __forceinline__ double block_reduce256(double v, double* sh4) {
    const int t = threadIdx.x;
    const int lane = t & 63, w = t >> 6;
    #pragma unroll
    for (int o = 32; o > 0; o >>= 1) v += __shfl_down(v, o, 64);
    if (lane == 0) sh4[w] = v;
    __syncthreads();
    double r = sh4[0] + sh4[1] + sh4[2] + sh4[3];
    __syncthreads();
    return r;
}

__global__ __launch_bounds__(256) void bhat_kernel(
    const unsigned int* __restrict__ gh, float* __restrict__ out) {
    __shared__ double sh4[4];
    const int t = threadIdx.x;  // bin index
    double result = 0.0;
    #pragma unroll
    for (int ch = 0; ch < NCH; ++ch) {
        const double h1 = (double)gh[ch * NBINS + t];
        const double h2 = (double)gh[(NCH + ch) * NBINS + t];
        const double s  = block_reduce256(sqrt(h1 * h2), sh4);
        const double s1 = block_reduce256(h1, sh4);
        const double s2 = block_reduce256(h2, sh4);
        const double denom = sqrt((s1 / (double)NBINS) * (s2 / (double)NBINS)) * (double)NBINS;
        const double v = 1.0 - s / denom;
        result += sqrt(v > 0.0 ? v : 0.0);
    }
    if (t == 0) out[0] = (float)result;
}

extern "C" void kernel_launch(void* const* d_in, const int* in_sizes, int n_in,
                              void* d_out, int out_size, void* d_ws, size_t ws_size,
                              hipStream_t stream) {
    const float* input = (const float*)d_in[0];
    const float* label = (const float*)d_in[1];
    float* out = (float*)d_out;
    unsigned int* gh = (unsigned int*)d_ws;

    // d_ws is poisoned with 0xAA before every timed launch — zero the hists.
    hipMemsetAsync(gh, 0, NHIST * sizeof(unsigned int), stream);

    hist_kernel<<<6 * BLOCKS_PER_JOB, THREADS, 0, stream>>>(input, label, gh);
    bhat_kernel<<<1, 256, 0, stream>>>(gh, out);
}